// Round 5
// baseline (2362.540 us; speedup 1.0000x reference)
//
#include <hip/hip_runtime.h>

#define BB 1024
#define TT 512
#define II 128
#define HH 64
#define G4 256   // 4*H
#define EE 128
#define CC 100
#define NB 4     // batch rows per block; 256 blocks = 1 per CU
#define NTH 512

typedef float f2 __attribute__((ext_vector_type(2)));
typedef float f4 __attribute__((ext_vector_type(4)));

__device__ __forceinline__ float sigm(float v) { return 1.f / (1.f + __expf(-v)); }
__device__ __forceinline__ float tanh_f(float v) {
    v = fminf(fmaxf(v, -15.f), 15.f);   // avoid inf/inf NaN
    float e = __expf(2.f * v);
    return (e - 1.f) / (e + 1.f);
}

// Round-7: kill the barrier-lockstep critical path.
// r4 lesson: doubling waves (occ 23->47%) made it WORSE -- all waves sync on
// the same block-wide chain (GEMV -> bar -> LDS zp round-trip combine -> bar).
// This version restructures ownership so the split-K reduce is IN-WAVE:
//   lane l of wave w: cell j = w*8 + (l>>3), K-slice q = l&7.
//   Thread owns ALL FOUR gate rows {j, j+64, j+128, j+192} of its cell.
//   - 8 K-partials of a cell sit in 8 consecutive lanes -> __shfl_xor 1,2,4
//     (no LDS, no barrier for the reduction)
//   - every lane applies the full i/f/g/o cell update for batch b = q&3
//     (lanes q>=4 duplicate harmlessly; c-state in registers)
//   - h0s/h1s DOUBLE-BUFFERED: GEMV reads [cur], activation writes [nxt]
//     -> ONE __syncthreads per step (was 2), zp LDS traffic gone (40KB->8KB)
// Sequence per step: L0 GEMV -> L0 reduce/act -> stage x -> L1 GEMV (h0(t-1),
// h1(t-2)) -> L1 reduce/act -> bar.  Cross-layer pipeline kept (L1 lags 1 step).
__global__ __launch_bounds__(NTH, 2)
void lstm2_persistent(const float* __restrict__ x,
                      const float* __restrict__ Wih0, const float* __restrict__ Whh0,
                      const float* __restrict__ bih0, const float* __restrict__ bhh0,
                      const float* __restrict__ Wih1, const float* __restrict__ Whh1,
                      const float* __restrict__ bih1, const float* __restrict__ bhh1,
                      float* __restrict__ hlast)
{
    __shared__ float xs[2][NB][II];       // double-buffered x tile (4 KB)
    __shared__ float h0s[2][NB][HH];      // double-buffered layer-0 hidden (2 KB)
    __shared__ float h1s[2][NB][HH];      // double-buffered layer-1 hidden (2 KB)

    const int tid = threadIdx.x;
    const int w   = tid >> 6;             // wave 0..7
    const int l   = tid & 63;
    const int q   = l & 7;                // K-slice 0..7
    const int jj  = l >> 3;               // 0..7
    const int j   = w * 8 + jj;           // cell 0..63
    const int b0  = blockIdx.x * NB;

    // ---- weights: 4 gate rows (i,f,g,o) of cell j, K-slice q. 160 floats ----
    f2 wx[4][8];   // Wih0 rows j+64g, cols [q*16, q*16+16)
    f2 wh[4][4];   // Whh0 rows j+64g, cols [q*8, q*8+8)
    f2 wu[4][4];   // Wih1 rows j+64g, cols [q*8, q*8+8)
    f2 wv[4][4];   // Whh1 rows j+64g, cols [q*8, q*8+8)

#define LOADR(dst, src, n4)                                          \
    do {                                                             \
        const f4* _s = (const f4*)(src);                             \
        _Pragma("unroll")                                            \
        for (int k = 0; k < (n4); ++k) {                             \
            f4 t = _s[k];                                            \
            dst[2*k]   = (f2){t.x, t.y};                             \
            dst[2*k+1] = (f2){t.z, t.w};                             \
        }                                                            \
    } while (0)

    float bz0[4], bz1[4];   // folded biases for the 4 gate rows
    #pragma unroll
    for (int g = 0; g < 4; ++g) {
        const int R = j + 64 * g;
        LOADR(wx[g], Wih0 + (size_t)R * II + q * 16, 4);
        LOADR(wh[g], Whh0 + (size_t)R * HH + q * 8, 2);
        LOADR(wu[g], Wih1 + (size_t)R * HH + q * 8, 2);
        LOADR(wv[g], Whh1 + (size_t)R * HH + q * 8, 2);
        bz0[g] = bih0[R] + bhh0[R];
        bz1[g] = bih1[R] + bhh1[R];
    }
#undef LOADR

    // zero-init both h buffers (1024 floats, 512 threads x 2)
    ((float*)h0s)[tid] = 0.f;
    ((float*)h1s)[tid] = 0.f;

    // x staging: thread (brow, bcol) loads x[b0+brow][t][bcol]; 2-step prefetch
    const int brow = tid >> 7, bcol = tid & 127;
    const float* xrow = x + ((size_t)(b0 + brow) * TT) * II + bcol;
    xs[0][brow][bcol] = xrow[0];
    float pre = xrow[II];                 // x(1)

    float c0 = 0.f, c1 = 0.f, h1v = 0.f;

    __syncthreads();

    // 4-way select z[q&3][g] (branchless cndmask chain; g compile-time)
#define SEL4(arr, g) ((q & 2) ? ((q & 1) ? arr[3][g] : arr[2][g])   \
                              : ((q & 1) ? arr[1][g] : arr[0][g]))

    // Invariant at loop top: h0s[cur] = h0(t-1), h1s[cur] = h1(t-2).
    for (int t = 0; t <= TT; ++t) {
        const int cur = t & 1, nxt = cur ^ 1;

        // ---- layer 0: GEMV + in-wave reduce + cell update (step t) ----
        if (t < TT) {
            float z0[NB][4];
            #pragma unroll
            for (int b = 0; b < NB; ++b) {
                f2 a0 = (f2){0.f,0.f}, a1 = (f2){0.f,0.f},
                   a2 = (f2){0.f,0.f}, a3 = (f2){0.f,0.f};
                const f4* xv = (const f4*)&xs[cur][b][q * 16];
                #pragma unroll
                for (int k = 0; k < 4; ++k) {
                    f4 v = xv[k];
                    f2 lo = (f2){v.x, v.y}, hi = (f2){v.z, v.w};
                    a0 += wx[0][2*k] * lo;  a0 += wx[0][2*k+1] * hi;
                    a1 += wx[1][2*k] * lo;  a1 += wx[1][2*k+1] * hi;
                    a2 += wx[2][2*k] * lo;  a2 += wx[2][2*k+1] * hi;
                    a3 += wx[3][2*k] * lo;  a3 += wx[3][2*k+1] * hi;
                }
                const f4* hv = (const f4*)&h0s[cur][b][q * 8];
                #pragma unroll
                for (int k = 0; k < 2; ++k) {
                    f4 v = hv[k];
                    f2 lo = (f2){v.x, v.y}, hi = (f2){v.z, v.w};
                    a0 += wh[0][2*k] * lo;  a0 += wh[0][2*k+1] * hi;
                    a1 += wh[1][2*k] * lo;  a1 += wh[1][2*k+1] * hi;
                    a2 += wh[2][2*k] * lo;  a2 += wh[2][2*k+1] * hi;
                    a3 += wh[3][2*k] * lo;  a3 += wh[3][2*k+1] * hi;
                }
                z0[b][0] = a0.x + a0.y;  z0[b][1] = a1.x + a1.y;
                z0[b][2] = a2.x + a2.y;  z0[b][3] = a3.x + a3.y;
            }
            // in-wave K-reduce over 8 consecutive lanes
            #pragma unroll
            for (int b = 0; b < NB; ++b)
                #pragma unroll
                for (int g = 0; g < 4; ++g) {
                    float v = z0[b][g];
                    v += __shfl_xor(v, 1);
                    v += __shfl_xor(v, 2);
                    v += __shfl_xor(v, 4);
                    z0[b][g] = v;
                }
            float zi = SEL4(z0, 0) + bz0[0];
            float zf = SEL4(z0, 1) + bz0[1];
            float zg = SEL4(z0, 2) + bz0[2];
            float zo = SEL4(z0, 3) + bz0[3];
            float gi = sigm(zi), gf = sigm(zf), gg = tanh_f(zg), go = sigm(zo);
            c0 = gf * c0 + gi * gg;
            float h = go * tanh_f(c0);
            if (q < 4) h0s[nxt][q][j] = h;   // lanes q>=4 are duplicates
        }

        // ---- x staging for t+1 (LDS write to xs[nxt]) ----
        if (t < TT - 1) {
            xs[nxt][brow][bcol] = pre;
            int tn = (t + 2 < TT) ? t + 2 : TT - 1;
            pre = xrow[(size_t)tn * II];
        }

        // ---- layer 1: GEMV + reduce + cell update (step t-1) ----
        // reads h0s[cur]=h0(t-1), h1s[cur]=h1(t-2) -- unaffected by the
        // h0s[nxt] writes above (different buffer)
        if (t >= 1) {
            float z1[NB][4];
            #pragma unroll
            for (int b = 0; b < NB; ++b) {
                f2 a0 = (f2){0.f,0.f}, a1 = (f2){0.f,0.f},
                   a2 = (f2){0.f,0.f}, a3 = (f2){0.f,0.f};
                const f4* hv0 = (const f4*)&h0s[cur][b][q * 8];
                #pragma unroll
                for (int k = 0; k < 2; ++k) {
                    f4 v = hv0[k];
                    f2 lo = (f2){v.x, v.y}, hi = (f2){v.z, v.w};
                    a0 += wu[0][2*k] * lo;  a0 += wu[0][2*k+1] * hi;
                    a1 += wu[1][2*k] * lo;  a1 += wu[1][2*k+1] * hi;
                    a2 += wu[2][2*k] * lo;  a2 += wu[2][2*k+1] * hi;
                    a3 += wu[3][2*k] * lo;  a3 += wu[3][2*k+1] * hi;
                }
                const f4* hv1 = (const f4*)&h1s[cur][b][q * 8];
                #pragma unroll
                for (int k = 0; k < 2; ++k) {
                    f4 v = hv1[k];
                    f2 lo = (f2){v.x, v.y}, hi = (f2){v.z, v.w};
                    a0 += wv[0][2*k] * lo;  a0 += wv[0][2*k+1] * hi;
                    a1 += wv[1][2*k] * lo;  a1 += wv[1][2*k+1] * hi;
                    a2 += wv[2][2*k] * lo;  a2 += wv[2][2*k+1] * hi;
                    a3 += wv[3][2*k] * lo;  a3 += wv[3][2*k+1] * hi;
                }
                z1[b][0] = a0.x + a0.y;  z1[b][1] = a1.x + a1.y;
                z1[b][2] = a2.x + a2.y;  z1[b][3] = a3.x + a3.y;
            }
            #pragma unroll
            for (int b = 0; b < NB; ++b)
                #pragma unroll
                for (int g = 0; g < 4; ++g) {
                    float v = z1[b][g];
                    v += __shfl_xor(v, 1);
                    v += __shfl_xor(v, 2);
                    v += __shfl_xor(v, 4);
                    z1[b][g] = v;
                }
            float zi = SEL4(z1, 0) + bz1[0];
            float zf = SEL4(z1, 1) + bz1[1];
            float zg = SEL4(z1, 2) + bz1[2];
            float zo = SEL4(z1, 3) + bz1[3];
            float gi = sigm(zi), gf = sigm(zf), gg = tanh_f(zg), go = sigm(zo);
            c1 = gf * c1 + gi * gg;
            h1v = go * tanh_f(c1);
            if (q < 4) h1s[nxt][q][j] = h1v;
        }

        __syncthreads();   // single barrier: [nxt] writes -> next-iter reads
    }
#undef SEL4

    // t=TT iteration computed h1(TT-1); value still in h1v on lanes q<4
    if (q < 4) hlast[(size_t)(b0 + q) * HH + j] = h1v;
}

// MLP head: one block per batch row. relu(hW_p^T+b) -> relu(.W_1^T+b) -> .W_2^T+b
__global__ __launch_bounds__(128, 4)
void head_kernel(const float* __restrict__ hlast,
                 const float* __restrict__ Wp, const float* __restrict__ bp,
                 const float* __restrict__ W1, const float* __restrict__ b1,
                 const float* __restrict__ W2, const float* __restrict__ b2,
                 float* __restrict__ out)
{
    __shared__ float hv[HH];
    __shared__ float emb[EE];
    __shared__ float hid[EE];
    const int b = blockIdx.x;
    const int e = threadIdx.x;   // 0..127
    if (e < HH) hv[e] = hlast[(size_t)b * HH + e];
    __syncthreads();
    float z = bp[e];
    #pragma unroll
    for (int j = 0; j < HH; ++j) z += Wp[e * HH + j] * hv[j];
    emb[e] = fmaxf(z, 0.f);
    __syncthreads();
    z = b1[e];
    #pragma unroll
    for (int j = 0; j < EE; ++j) z += W1[e * EE + j] * emb[j];
    hid[e] = fmaxf(z, 0.f);
    __syncthreads();
    if (e < CC) {
        z = b2[e];
        #pragma unroll
        for (int j = 0; j < EE; ++j) z += W2[e * EE + j] * hid[j];
        out[(size_t)b * CC + e] = z;
    }
}

extern "C" void kernel_launch(void* const* d_in, const int* in_sizes, int n_in,
                              void* d_out, int out_size, void* d_ws, size_t ws_size,
                              hipStream_t stream)
{
    const float* x    = (const float*)d_in[0];
    const float* Wih0 = (const float*)d_in[1];
    const float* Whh0 = (const float*)d_in[2];
    const float* bih0 = (const float*)d_in[3];
    const float* bhh0 = (const float*)d_in[4];
    const float* Wih1 = (const float*)d_in[5];
    const float* Whh1 = (const float*)d_in[6];
    const float* bih1 = (const float*)d_in[7];
    const float* bhh1 = (const float*)d_in[8];
    const float* Wp   = (const float*)d_in[9];
    const float* bp   = (const float*)d_in[10];
    const float* W1   = (const float*)d_in[11];
    const float* b1   = (const float*)d_in[12];
    const float* W2   = (const float*)d_in[13];
    const float* b2   = (const float*)d_in[14];

    float* hlast = (float*)d_ws;           // 1024*64 fp32 = 256 KB
    float* out   = (float*)d_out;          // [1024, 100] fp32

    lstm2_persistent<<<BB / NB, NTH, 0, stream>>>(x, Wih0, Whh0, bih0, bhh0,
                                                  Wih1, Whh1, bih1, bhh1, hlast);
    head_kernel<<<BB, EE, 0, stream>>>(hlast, Wp, bp, W1, b1, W2, b2, out);
}

// Round 6
// 1591.393 us; speedup vs baseline: 1.4846x; 1.4846x over previous
//
#include <hip/hip_runtime.h>

#define BB 1024
#define TT 512
#define II 128
#define HH 64
#define G4 256   // 4*H
#define EE 128
#define CC 100
#define NB 4     // batch rows per block; 256 blocks = 1 per CU
#define NTH 512
#define SK 8     // K-eighths, one per wave (wave-uniform -> broadcast reads)

typedef float f2 __attribute__((ext_vector_type(2)));
typedef float f4 __attribute__((ext_vector_type(4)));

__device__ __forceinline__ float sigm(float v) { return 1.f / (1.f + __expf(-v)); }
__device__ __forceinline__ float tanh_f(float v) {
    v = fminf(fmaxf(v, -15.f), 15.f);   // avoid inf/inf NaN
    float e = __expf(2.f * v);
    return (e - 1.f) / (e + 1.f);
}

// Round-8: halve LDS-pipe traffic, keep every r3-proven invariant.
// r5 lesson: per-lane K-slice -> 7.97e7 bank conflicts + 96 shfl (= LDS-pipe
// ops on CDNA) -> LDS-pipe-bound at 2362us. r3 (1444us) is itself co-limited
// by the per-CU LDS pipe (~80 broadcast reads + zp round-trip per thread).
// This version keeps r3's skeleton (wave-uniform broadcasts, zp LDS round
// trip, 2 barriers, cross-layer pipeline) but remaps ownership:
//   wave w = K-eighth (wave-uniform), lane l = cell l,
//   thread owns ALL FOUR gate rows {l, l+64, l+128, l+192}, K-slice w.
// -> each broadcast ds_read_b128 feeds 4 rows (8 pk-FMA): reads 80 -> 40
// -> 4 gate partials per (cell,b) live in ONE thread: zp packs to f4:
//    writes 8xb32 -> 4xb128 (contiguous per lane), combine 16xb32 -> 8xb128
// FMA count and weight budget (160 floats) unchanged.
__global__ __launch_bounds__(NTH, 2)
void lstm2_persistent(const float* __restrict__ x,
                      const float* __restrict__ Wih0, const float* __restrict__ Whh0,
                      const float* __restrict__ bih0, const float* __restrict__ bhh0,
                      const float* __restrict__ Wih1, const float* __restrict__ Whh1,
                      const float* __restrict__ bih1, const float* __restrict__ bhh1,
                      float* __restrict__ hlast)
{
    __shared__ float xs[2][NB][II];      // double-buffered x tile (4 KB)
    __shared__ float h0s[NB][HH];        // layer-0 hidden h0(t-1) (1 KB)
    __shared__ float h1s[NB][HH];        // layer-1 hidden h1(t-2) (1 KB)
    __shared__ f4 zp0[SK][NB][HH];       // layer-0 partials, f4 = 4 gates (32 KB)
    __shared__ f4 zp1[SK][NB][HH];       // layer-1 partials (32 KB)

    const int tid = threadIdx.x;
    const int w   = tid >> 6;            // K-eighth 0..7 (wave id, uniform)
    const int l   = tid & 63;            // cell 0..63
    const int b0  = blockIdx.x * NB;

    // ---- weights: 4 gate rows (i,f,g,o) of cell l, K-slice w. 160 floats ----
    f2 wx[4][8];   // Wih0 rows l+64g, x-cols [w*16, w*16+16)
    f2 wh[4][4];   // Whh0 rows l+64g, h-cols [w*8, w*8+8)
    f2 wu[4][4];   // Wih1 rows l+64g, cols [w*8, w*8+8)
    f2 wv[4][4];   // Whh1 rows l+64g, cols [w*8, w*8+8)

#define LOADR(dst, src, n4)                                          \
    do {                                                             \
        const f4* _s = (const f4*)(src);                             \
        _Pragma("unroll")                                            \
        for (int k = 0; k < (n4); ++k) {                             \
            f4 t = _s[k];                                            \
            dst[2*k]   = (f2){t.x, t.y};                             \
            dst[2*k+1] = (f2){t.z, t.w};                             \
        }                                                            \
    } while (0)

    #pragma unroll
    for (int g = 0; g < 4; ++g) {
        const int R = l + 64 * g;
        LOADR(wx[g], Wih0 + (size_t)R * II + w * 16, 4);
        LOADR(wh[g], Whh0 + (size_t)R * HH + w * 8, 2);
        LOADR(wu[g], Wih1 + (size_t)R * HH + w * 8, 2);
        LOADR(wv[g], Whh1 + (size_t)R * HH + w * 8, 2);
    }
#undef LOADR

#define PINF(arr, n)                                                 \
    do {                                                             \
        f2* _p = (f2*)(arr);                                         \
        _Pragma("unroll")                                            \
        for (int _i = 0; _i < (n); ++_i) asm volatile("" : "+v"(_p[_i])); \
    } while (0)

    // combine roles: waves 0-3 -> layer-0 cell (cb,cj); waves 4-7 -> layer-1
    const int lay = tid >> 8;            // wave-uniform
    const int cb  = (tid >> 6) & 3, cj = tid & 63;
    f4 bz;                               // folded biases for cell cj's 4 gates
    {
        const float* bih = lay ? bih1 : bih0;
        const float* bhh = lay ? bhh1 : bhh0;
        bz = (f4){bih[cj]       + bhh[cj],
                  bih[64 + cj]  + bhh[64 + cj],
                  bih[128 + cj] + bhh[128 + cj],
                  bih[192 + cj] + bhh[192 + cj]};
    }
    float c_reg = 0.f, hl = 0.f;

    if (tid < 256) ((float*)h0s)[tid] = 0.f;
    else           ((float*)h1s)[tid - 256] = 0.f;

    // x staging: thread (brow, bcol) loads x[b0+brow][t][bcol]; 2-step prefetch
    const int brow = tid >> 7, bcol = tid & 127;
    const float* xrow = x + ((size_t)(b0 + brow) * TT) * II + bcol;
    xs[0][brow][bcol] = xrow[0];
    float pre = xrow[II];                // x(1)

    __syncthreads();

    // Pipelined (r3-proven): iter t computes z0(t) [t<TT] and z1(t-1) [t>=1],
    // then one fused combine. Loop-top invariant: h0s=h0(t-1), h1s=h1(t-2).
    for (int t = 0; t <= TT; ++t) {
        const int cur = t & 1, nxt = cur ^ 1;

        PINF(wx, 32); PINF(wh, 16); PINF(wu, 16); PINF(wv, 16);

        // ---- GEMV phase ----
        if (t < TT) {   // layer-0 partials for step t
            #pragma unroll
            for (int b = 0; b < NB; ++b) {
                f2 a0 = (f2){0.f,0.f}, a1 = (f2){0.f,0.f},
                   a2 = (f2){0.f,0.f}, a3 = (f2){0.f,0.f};
                const f4* xv = (const f4*)&xs[cur][b][w * 16];
                #pragma unroll
                for (int k = 0; k < 4; ++k) {
                    f4 v = xv[k];                    // wave-uniform -> broadcast
                    f2 lo = (f2){v.x, v.y}, hi = (f2){v.z, v.w};
                    a0 += wx[0][2*k] * lo;  a0 += wx[0][2*k+1] * hi;
                    a1 += wx[1][2*k] * lo;  a1 += wx[1][2*k+1] * hi;
                    a2 += wx[2][2*k] * lo;  a2 += wx[2][2*k+1] * hi;
                    a3 += wx[3][2*k] * lo;  a3 += wx[3][2*k+1] * hi;
                }
                const f4* hv = (const f4*)&h0s[b][w * 8];
                #pragma unroll
                for (int k = 0; k < 2; ++k) {
                    f4 v = hv[k];
                    f2 lo = (f2){v.x, v.y}, hi = (f2){v.z, v.w};
                    a0 += wh[0][2*k] * lo;  a0 += wh[0][2*k+1] * hi;
                    a1 += wh[1][2*k] * lo;  a1 += wh[1][2*k+1] * hi;
                    a2 += wh[2][2*k] * lo;  a2 += wh[2][2*k+1] * hi;
                    a3 += wh[3][2*k] * lo;  a3 += wh[3][2*k+1] * hi;
                }
                zp0[w][b][l] = (f4){a0.x + a0.y, a1.x + a1.y,
                                    a2.x + a2.y, a3.x + a3.y};   // one b128
            }
        }
        if (t >= 1) {   // layer-1 partials for step t-1 (h0(t-1), h1(t-2))
            #pragma unroll
            for (int b = 0; b < NB; ++b) {
                f2 a0 = (f2){0.f,0.f}, a1 = (f2){0.f,0.f},
                   a2 = (f2){0.f,0.f}, a3 = (f2){0.f,0.f};
                const f4* hv0 = (const f4*)&h0s[b][w * 8];
                #pragma unroll
                for (int k = 0; k < 2; ++k) {
                    f4 v = hv0[k];
                    f2 lo = (f2){v.x, v.y}, hi = (f2){v.z, v.w};
                    a0 += wu[0][2*k] * lo;  a0 += wu[0][2*k+1] * hi;
                    a1 += wu[1][2*k] * lo;  a1 += wu[1][2*k+1] * hi;
                    a2 += wu[2][2*k] * lo;  a2 += wu[2][2*k+1] * hi;
                    a3 += wu[3][2*k] * lo;  a3 += wu[3][2*k+1] * hi;
                }
                const f4* hv1 = (const f4*)&h1s[b][w * 8];
                #pragma unroll
                for (int k = 0; k < 2; ++k) {
                    f4 v = hv1[k];
                    f2 lo = (f2){v.x, v.y}, hi = (f2){v.z, v.w};
                    a0 += wv[0][2*k] * lo;  a0 += wv[0][2*k+1] * hi;
                    a1 += wv[1][2*k] * lo;  a1 += wv[1][2*k+1] * hi;
                    a2 += wv[2][2*k] * lo;  a2 += wv[2][2*k+1] * hi;
                    a3 += wv[3][2*k] * lo;  a3 += wv[3][2*k+1] * hi;
                }
                zp1[w][b][l] = (f4){a0.x + a0.y, a1.x + a1.y,
                                    a2.x + a2.y, a3.x + a3.y};
            }
        }
        // x staging for t+1 (overlaps GEMV tail)
        if (t < TT - 1) {
            xs[nxt][brow][bcol] = pre;
            int tn = (t + 2 < TT) ? t + 2 : TT - 1;
            pre = xrow[(size_t)tn * II];
        }
        __syncthreads();   // bar1: zp*/h* handoff to combine

        // ---- fused combine: waves 0-3 -> cell0(t), waves 4-7 -> cell1(t-1) ----
        {
            const bool act = lay ? (t >= 1) : (t < TT);   // wave-uniform
            if (act) {
                const f4* zpp = lay ? &zp1[0][cb][cj] : &zp0[0][cb][cj];
                f4 z = bz;
                #pragma unroll
                for (int p = 0; p < SK; ++p)
                    z += zpp[(size_t)p * NB * HH];        // 8x b128, contiguous lanes
                float gi = sigm(z.x), gf = sigm(z.y);
                float gg = tanh_f(z.z), go = sigm(z.w);
                c_reg = gf * c_reg + gi * gg;
                float h = go * tanh_f(c_reg);
                if (lay == 0) h0s[cb][cj] = h;
                else          { h1s[cb][cj] = h; hl = h; }
            }
        }
        __syncthreads();   // bar2: h* handoff to next GEMV / zp* reuse
    }
#undef PINF

    // lay-1 combine thread computed h1(TT-1) at iter TT; value in hl
    if (lay == 1) hlast[(size_t)(b0 + cb) * HH + cj] = hl;
}

// MLP head: one block per batch row. relu(hW_p^T+b) -> relu(.W_1^T+b) -> .W_2^T+b
__global__ __launch_bounds__(128, 4)
void head_kernel(const float* __restrict__ hlast,
                 const float* __restrict__ Wp, const float* __restrict__ bp,
                 const float* __restrict__ W1, const float* __restrict__ b1,
                 const float* __restrict__ W2, const float* __restrict__ b2,
                 float* __restrict__ out)
{
    __shared__ float hv[HH];
    __shared__ float emb[EE];
    __shared__ float hid[EE];
    const int b = blockIdx.x;
    const int e = threadIdx.x;   // 0..127
    if (e < HH) hv[e] = hlast[(size_t)b * HH + e];
    __syncthreads();
    float z = bp[e];
    #pragma unroll
    for (int j = 0; j < HH; ++j) z += Wp[e * HH + j] * hv[j];
    emb[e] = fmaxf(z, 0.f);
    __syncthreads();
    z = b1[e];
    #pragma unroll
    for (int j = 0; j < EE; ++j) z += W1[e * EE + j] * emb[j];
    hid[e] = fmaxf(z, 0.f);
    __syncthreads();
    if (e < CC) {
        z = b2[e];
        #pragma unroll
        for (int j = 0; j < EE; ++j) z += W2[e * EE + j] * hid[j];
        out[(size_t)b * CC + e] = z;
    }
}

extern "C" void kernel_launch(void* const* d_in, const int* in_sizes, int n_in,
                              void* d_out, int out_size, void* d_ws, size_t ws_size,
                              hipStream_t stream)
{
    const float* x    = (const float*)d_in[0];
    const float* Wih0 = (const float*)d_in[1];
    const float* Whh0 = (const float*)d_in[2];
    const float* bih0 = (const float*)d_in[3];
    const float* bhh0 = (const float*)d_in[4];
    const float* Wih1 = (const float*)d_in[5];
    const float* Whh1 = (const float*)d_in[6];
    const float* bih1 = (const float*)d_in[7];
    const float* bhh1 = (const float*)d_in[8];
    const float* Wp   = (const float*)d_in[9];
    const float* bp   = (const float*)d_in[10];
    const float* W1   = (const float*)d_in[11];
    const float* b1   = (const float*)d_in[12];
    const float* W2   = (const float*)d_in[13];
    const float* b2   = (const float*)d_in[14];

    float* hlast = (float*)d_ws;           // 1024*64 fp32 = 256 KB
    float* out   = (float*)d_out;          // [1024, 100] fp32

    lstm2_persistent<<<BB / NB, NTH, 0, stream>>>(x, Wih0, Whh0, bih0, bhh0,
                                                  Wih1, Whh1, bih1, bhh1, hlast);
    head_kernel<<<BB, EE, 0, stream>>>(hlast, Wp, bp, W1, b1, W2, b2, out);
}